// Round 11
// baseline (184.866 us; speedup 1.0000x reference)
//
#include <hip/hip_runtime.h>
#include <stdint.h>

#define S_LEN 80
#define H_DIM 128
#define ROWS 10       // real lane rows per block (2560 = 256 blocks * 10)
#define MROWS 16      // padded MFMA M-tile
#define BLOCK_T 1024  // 16 waves -> 4 waves/SIMD (the occupancy lever)

#define NL2E  (-1.44269504088896f)   // -log2(e)
#define N2L2E (-2.88539008177793f)   // -2*log2(e)

typedef __bf16 bf16x8 __attribute__((ext_vector_type(8)));
typedef unsigned short u16x8 __attribute__((ext_vector_type(8)));
typedef float f32x4 __attribute__((ext_vector_type(4)));
typedef float f32x2 __attribute__((ext_vector_type(2)));

__device__ __forceinline__ float sigy(float y) {
    return __builtin_amdgcn_rcpf(1.0f + __builtin_amdgcn_exp2f(y));
}
__device__ __forceinline__ float tanhy(float y) {
    return 2.0f * __builtin_amdgcn_rcpf(1.0f + __builtin_amdgcn_exp2f(y)) - 1.0f;
}
__device__ __forceinline__ unsigned short bfbits(float f) {
    return __builtin_bit_cast(unsigned short, (__bf16)f);   // HW RNE cvt
}

#define MFMA(A, B, C) __builtin_amdgcn_mfma_f32_16x16x32_bf16((A), (B), (C), 0, 0, 0)
#define WB(W) __builtin_bit_cast(bf16x8, W)

// R11 GATE-SPLIT: 16 waves. Wave w: slice=(w&7) -> hcols [slice*16,+16);
// role=(w>>3): 0 = IF waves (gates i,f), 1 = GO waves (gates g,o).
// Weights/wave = 2 gates x 4kt x 2 mats = 64 AGPR (half of before) -> total
// regs <= 128/wave -> 4 waves/SIMD (each SIMD: 2 IF + 2 GO via wv%4).
// Per step: all waves hh-GEMM (2 gates, 8 MFMA); GO computes tanh(g),sig(o)
// -> go_lds; B1; IF does cell+h-store WHILE GO does next ih-GEMM; B2.
// Role regions are small single-copy blocks (R6's miscompile was dual-inlined
// bodies at the 256-reg cap — avoided). W_emb/b_emb live in LDS (reg trim).
//
// Swizzle discipline: key = (row&7)<<4 spans BITS 4-6 -> XOR onto the FULL
// logical byte offset (incl. kt*64, bits 6-7), never onto a pre-XORed base.
__global__ __launch_bounds__(BLOCK_T, 4)
void lane_lstm(const float* __restrict__ lanes,
               const float* __restrict__ W_emb, const float* __restrict__ b_emb,
               const float* __restrict__ W_ih,  const float* __restrict__ W_hh,
               const float* __restrict__ b_ih,  const float* __restrict__ b_hh,
               float* __restrict__ out, int BL)
{
    __shared__ __align__(16) float ext_lds[S_LEN * ROWS * 5];           // 16000 B
    __shared__ __align__(16) unsigned short emb_lds[2][MROWS * H_DIM];  // 2x4096 B
    __shared__ __align__(16) unsigned short h_lds[2][MROWS * H_DIM];    // 2x4096 B
    __shared__ __align__(16) float go_lds[MROWS * H_DIM * 2];           // 16384 B
    __shared__ __align__(16) float wemb_lds[6 * H_DIM];                 // 3072 B [d][c], d=5 -> bias
    __shared__ int valid_lds[MROWS];

    const int t    = threadIdx.x;
    const int lane = t & 63;
    const int wv   = t >> 6;          // 0..15
    const int role = wv >> 3;         // 0 = IF (i,f), 1 = GO (g,o)
    const int ga   = role * 2;        // gate a: 0 or 2
    const int gb   = ga + 1;          // gate b: 1 or 3
    const int row0 = blockIdx.x * ROWS;

    const int hcol = (wv & 7) * 16 + (lane & 15);
    const int kb0  = (lane >> 4) << 3;

    if (t < MROWS) valid_lds[t] = 1;
    *(uint32_t*)((char*)&h_lds[0][0] + t * 4) = 0;   // h0 = 0 (1024*4 = 4096 B)
    if (t < 6 * H_DIM) {                             // W_emb/b_emb -> LDS [d][c]
        int d = t >> 7, c = t & 127;
        wemb_lds[t] = (d < 5) ? W_emb[c * 5 + d] : b_emb[c];
    }
    __syncthreads();   // valid/h0/wemb init done before ext clears valid

    // ---- ext features (x,y,dx,dy,yaw) ----
    for (int p = t; p < S_LEN * ROWS; p += BLOCK_T) {
        int s = p / ROWS;
        int r = p - s * ROWS;
        int bl = row0 + r;
        float x = 0.f, y = 0.f, dx = 0.f, dy = 0.f;
        if (bl < BL) {
            const float* lp = lanes + ((size_t)s * BL + bl) * 2;
            x = lp[0]; y = lp[1];
            if (s > 0) {
                const float* lq = lanes + ((size_t)(s - 1) * BL + bl) * 2;
                dx = x - lq[0]; dy = y - lq[1];
            }
            if (__builtin_isnan(x) || __builtin_isnan(y)) valid_lds[r] = 0;
        }
        float* e = &ext_lds[p * 5];
        e[0] = x; e[1] = y; e[2] = dx; e[3] = dy; e[4] = atan2f(y, x);
    }

    // ---- wave-owned weight B-frags (2 gates), PRE-SCALED, AGPR-pinned ----
    // B-frag: col = g*128 + hcol, k = kt*32 + (lane>>4)*8 + j (same map as A).
    f32x4 wia[4], wib[4], wha[4], whb[4];
    float ba, bb;
    {
        const float sca = (ga == 2) ? N2L2E : NL2E;   // gate g gets -2log2e
        ba = (b_ih[ga * H_DIM + hcol] + b_hh[ga * H_DIM + hcol]) * sca;
        bb = (b_ih[gb * H_DIM + hcol] + b_hh[gb * H_DIM + hcol]) * NL2E;
        #pragma unroll
        for (int kt = 0; kt < 4; ++kt) {
            const float* pia = &W_ih[(size_t)(ga * H_DIM + hcol) * H_DIM + kt * 32 + kb0];
            const float* pib = &W_ih[(size_t)(gb * H_DIM + hcol) * H_DIM + kt * 32 + kb0];
            const float* pha = &W_hh[(size_t)(ga * H_DIM + hcol) * H_DIM + kt * 32 + kb0];
            const float* phb = &W_hh[(size_t)(gb * H_DIM + hcol) * H_DIM + kt * 32 + kb0];
            u16x8 ta, tb, tc, td;
            #pragma unroll
            for (int j = 0; j < 8; ++j) {
                ta[j] = bfbits(pia[j] * sca); tb[j] = bfbits(pib[j] * NL2E);
                tc[j] = bfbits(pha[j] * sca); td[j] = bfbits(phb[j] * NL2E);
            }
            wia[kt] = __builtin_bit_cast(f32x4, ta);
            wib[kt] = __builtin_bit_cast(f32x4, tb);
            wha[kt] = __builtin_bit_cast(f32x4, tc);
            whb[kt] = __builtin_bit_cast(f32x4, td);
        }
    }
    #pragma unroll
    for (int kt = 0; kt < 4; ++kt) {
        asm volatile("" : "+a"(wia[kt])); asm volatile("" : "+a"(wib[kt]));
        asm volatile("" : "+a"(wha[kt])); asm volatile("" : "+a"(whb[kt]));
    }

    // ---- emb duty: wave wv handles row wv (all 16), 2 cols/thread ----
    const int er  = wv;
    const int ec  = lane << 1;
    const int ebyte = ((er << 8) + (ec << 1)) ^ ((er & 7) << 4);
    auto emb_store = [&](int sx, int b) {
        float x0 = 0.f, x1 = 0.f, x2 = 0.f, x3 = 0.f, x4 = 0.f;
        if (er < ROWS && valid_lds[er] && row0 + er < BL) {
            const float* e = &ext_lds[(sx * ROWS + er) * 5];
            x0 = e[0]; x1 = e[1]; x2 = e[2]; x3 = e[3]; x4 = e[4];
        }
        f32x2 w0 = *(const f32x2*)&wemb_lds[0 * H_DIM + ec];
        f32x2 w1 = *(const f32x2*)&wemb_lds[1 * H_DIM + ec];
        f32x2 w2 = *(const f32x2*)&wemb_lds[2 * H_DIM + ec];
        f32x2 w3 = *(const f32x2*)&wemb_lds[3 * H_DIM + ec];
        f32x2 w4 = *(const f32x2*)&wemb_lds[4 * H_DIM + ec];
        f32x2 bz = *(const f32x2*)&wemb_lds[5 * H_DIM + ec];
        float a0 = bz[0] + w0[0]*x0 + w1[0]*x1 + w2[0]*x2 + w3[0]*x3 + w4[0]*x4;
        float a1 = bz[1] + w0[1]*x0 + w1[1]*x1 + w2[1]*x2 + w3[1]*x3 + w4[1]*x4;
        uint32_t pk = (uint32_t)bfbits(fmaxf(a0, 0.f)) |
                      ((uint32_t)bfbits(fmaxf(a1, 0.f)) << 16);
        *(uint32_t*)((char*)&emb_lds[b][0] + ebyte) = pk;
    };

    // A-frag: row = lane&15, byte = (row<<8) + (lane>>4)*16 + kt*64, full XOR.
    const int arow  = lane & 15;
    const int akey  = (arow & 7) << 4;
    const int abase = (arow << 8) + ((lane >> 4) << 4);
    const int crow  = (lane >> 4) << 2;   // C/D (m89): row=(lane>>4)*4+i, col=lane&15
    const int gobyte = (crow * H_DIM + hcol) * 8;   // f32x2 per element

    __syncthreads();       // ext + valid ready
    emb_store(0, 0);
    __syncthreads();       // emb[0] visible

    // ---- prologue: xa/xb = bias + emb[0] @ W_ih^T (this wave's 2 gates) ----
    f32x4 xa, xb;
    {
        const char* eb = (const char*)&emb_lds[0][0];
        f32x4 bva, bvb;
        bva[0]=ba; bva[1]=ba; bva[2]=ba; bva[3]=ba;
        bvb[0]=bb; bvb[1]=bb; bvb[2]=bb; bvb[3]=bb;
        #pragma unroll
        for (int kt = 0; kt < 4; ++kt) {
            bf16x8 ae = *(const bf16x8*)(eb + ((abase + kt * 64) ^ akey));
            if (kt == 0) { xa = MFMA(ae, WB(wia[0]), bva); xb = MFMA(ae, WB(wib[0]), bvb); }
            else         { xa = MFMA(ae, WB(wia[kt]), xa); xb = MFMA(ae, WB(wib[kt]), xb); }
        }
    }
    emb_store(1, 1);
    __syncthreads();       // emb[1] visible

    float c0 = 0.f, c1 = 0.f, c2 = 0.f, c3 = 0.f;   // live only in IF waves

    for (int s = 0; s < S_LEN - 1; ++s) {
        const char* hb = (const char*)&h_lds[s & 1][0];
        const char* en = (const char*)&emb_lds[(s + 1) & 1][0];

        // ---- hh GEMM (this wave's 2 gates): v = x + h[s] @ W_hh^T ----
        f32x4 va = xa, vb = xb;
        #pragma unroll
        for (int kt = 0; kt < 4; ++kt) {
            bf16x8 ah = *(const bf16x8*)(hb + ((abase + kt * 64) ^ akey));
            va = MFMA(ah, WB(wha[kt]), va);
            vb = MFMA(ah, WB(whb[kt]), vb);
        }

        float p0, p1, p2, p3, q0, q1, q2, q3;
        if (role) {
            // GO: tanh(g), sig(o) -> exchange buffer
            f32x2 w;
            w[0] = tanhy(va[0]); w[1] = sigy(vb[0]);
            *(f32x2*)((char*)&go_lds[0] + gobyte)        = w;
            w[0] = tanhy(va[1]); w[1] = sigy(vb[1]);
            *(f32x2*)((char*)&go_lds[0] + gobyte + 1024) = w;
            w[0] = tanhy(va[2]); w[1] = sigy(vb[2]);
            *(f32x2*)((char*)&go_lds[0] + gobyte + 2048) = w;
            w[0] = tanhy(va[3]); w[1] = sigy(vb[3]);
            *(f32x2*)((char*)&go_lds[0] + gobyte + 3072) = w;
        } else {
            // IF: sig(i), sig(f) stay in registers across B1
            p0 = sigy(va[0]); p1 = sigy(va[1]); p2 = sigy(va[2]); p3 = sigy(va[3]);
            q0 = sigy(vb[0]); q1 = sigy(vb[1]); q2 = sigy(vb[2]); q3 = sigy(vb[3]);
        }
        __syncthreads();   // B1: gate exchange ready (converged barrier)

        if (!role) {
            // IF: cell + h store (GO waves run the ih GEMM below meanwhile)
            char* hn = (char*)&h_lds[(s + 1) & 1][0];
            f32x2 w;
            w = *(const f32x2*)((const char*)&go_lds[0] + gobyte);
            c0 = q0 * c0 + p0 * w[0];
            *(unsigned short*)(hn + (((crow + 0) << 8) + (hcol << 1) ^ (((crow + 0) & 7) << 4)))
                = bfbits(w[1] * tanhy(c0 * N2L2E));
            w = *(const f32x2*)((const char*)&go_lds[0] + gobyte + 1024);
            c1 = q1 * c1 + p1 * w[0];
            *(unsigned short*)(hn + (((crow + 1) << 8) + (hcol << 1) ^ (((crow + 1) & 7) << 4)))
                = bfbits(w[1] * tanhy(c1 * N2L2E));
            w = *(const f32x2*)((const char*)&go_lds[0] + gobyte + 2048);
            c2 = q2 * c2 + p2 * w[0];
            *(unsigned short*)(hn + (((crow + 2) << 8) + (hcol << 1) ^ (((crow + 2) & 7) << 4)))
                = bfbits(w[1] * tanhy(c2 * N2L2E));
            w = *(const f32x2*)((const char*)&go_lds[0] + gobyte + 3072);
            c3 = q3 * c3 + p3 * w[0];
            *(unsigned short*)(hn + (((crow + 3) << 8) + (hcol << 1) ^ (((crow + 3) & 7) << 4)))
                = bfbits(w[1] * tanhy(c3 * N2L2E));
        }

        // ---- uniform: ih GEMM for s+1 + next emb ----
        {
            f32x4 bva, bvb;
            bva[0]=ba; bva[1]=ba; bva[2]=ba; bva[3]=ba;
            bvb[0]=bb; bvb[1]=bb; bvb[2]=bb; bvb[3]=bb;
            #pragma unroll
            for (int kt = 0; kt < 4; ++kt) {
                bf16x8 ae = *(const bf16x8*)(en + ((abase + kt * 64) ^ akey));
                if (kt == 0) { xa = MFMA(ae, WB(wia[0]), bva); xb = MFMA(ae, WB(wib[0]), bvb); }
                else         { xa = MFMA(ae, WB(wia[kt]), xa); xb = MFMA(ae, WB(wib[kt]), xb); }
            }
        }
        if (s + 2 < S_LEN) emb_store(s + 2, s & 1);
        __syncthreads();   // B2: h[s+1], emb[s+2], gate-buffer consumed
    }

    // ---- peeled final step s = 79: hh + exchange + cell + global out ----
    {
        const char* hb = (const char*)&h_lds[(S_LEN - 1) & 1][0];
        f32x4 va = xa, vb = xb;
        #pragma unroll
        for (int kt = 0; kt < 4; ++kt) {
            bf16x8 ah = *(const bf16x8*)(hb + ((abase + kt * 64) ^ akey));
            va = MFMA(ah, WB(wha[kt]), va);
            vb = MFMA(ah, WB(whb[kt]), vb);
        }
        float p0, p1, p2, p3, q0, q1, q2, q3;
        if (role) {
            f32x2 w;
            w[0] = tanhy(va[0]); w[1] = sigy(vb[0]);
            *(f32x2*)((char*)&go_lds[0] + gobyte)        = w;
            w[0] = tanhy(va[1]); w[1] = sigy(vb[1]);
            *(f32x2*)((char*)&go_lds[0] + gobyte + 1024) = w;
            w[0] = tanhy(va[2]); w[1] = sigy(vb[2]);
            *(f32x2*)((char*)&go_lds[0] + gobyte + 2048) = w;
            w[0] = tanhy(va[3]); w[1] = sigy(vb[3]);
            *(f32x2*)((char*)&go_lds[0] + gobyte + 3072) = w;
        } else {
            p0 = sigy(va[0]); p1 = sigy(va[1]); p2 = sigy(va[2]); p3 = sigy(va[3]);
            q0 = sigy(vb[0]); q1 = sigy(vb[1]); q2 = sigy(vb[2]); q3 = sigy(vb[3]);
        }
        __syncthreads();
        if (!role) {
            f32x2 w;
            w = *(const f32x2*)((const char*)&go_lds[0] + gobyte);
            c0 = q0 * c0 + p0 * w[0];
            float h0v = w[1] * tanhy(c0 * N2L2E);
            w = *(const f32x2*)((const char*)&go_lds[0] + gobyte + 1024);
            c1 = q1 * c1 + p1 * w[0];
            float h1v = w[1] * tanhy(c1 * N2L2E);
            w = *(const f32x2*)((const char*)&go_lds[0] + gobyte + 2048);
            c2 = q2 * c2 + p2 * w[0];
            float h2v = w[1] * tanhy(c2 * N2L2E);
            w = *(const f32x2*)((const char*)&go_lds[0] + gobyte + 3072);
            c3 = q3 * c3 + p3 * w[0];
            float h3v = w[1] * tanhy(c3 * N2L2E);
            if (crow + 0 < ROWS && row0 + crow + 0 < BL) out[(size_t)(row0 + crow + 0) * H_DIM + hcol] = h0v;
            if (crow + 1 < ROWS && row0 + crow + 1 < BL) out[(size_t)(row0 + crow + 1) * H_DIM + hcol] = h1v;
            if (crow + 2 < ROWS && row0 + crow + 2 < BL) out[(size_t)(row0 + crow + 2) * H_DIM + hcol] = h2v;
            if (crow + 3 < ROWS && row0 + crow + 3 < BL) out[(size_t)(row0 + crow + 3) * H_DIM + hcol] = h3v;
        }
    }
}

extern "C" void kernel_launch(void* const* d_in, const int* in_sizes, int n_in,
                              void* d_out, int out_size, void* d_ws, size_t ws_size,
                              hipStream_t stream) {
    const float* lanes = (const float*)d_in[1];
    const float* W_emb = (const float*)d_in[2];
    const float* b_emb = (const float*)d_in[3];
    const float* W_ih  = (const float*)d_in[4];
    const float* W_hh  = (const float*)d_in[5];
    const float* b_ih  = (const float*)d_in[6];
    const float* b_hh  = (const float*)d_in[7];
    float* out = (float*)d_out;

    const int BL   = in_sizes[1] / (2 * S_LEN);   // 2560
    const int grid = (BL + ROWS - 1) / ROWS;      // 256 blocks -> 1 per CU

    lane_lstm<<<dim3(grid), dim3(BLOCK_T), 0, stream>>>(
        lanes, W_emb, b_emb, W_ih, W_hh, b_ih, b_hh, out, BL);
}

// Round 12
// 120.091 us; speedup vs baseline: 1.5394x; 1.5394x over previous
//
#include <hip/hip_runtime.h>
#include <stdint.h>

#define S_LEN 80
#define H_DIM 128
#define ROWS 10      // real lane rows per block (2560 = 256 blocks * 10)
#define MROWS 16     // padded MFMA M-tile
#define BLOCK_T 512  // 8 waves, 2/SIMD (256 regs/wave: 128 VGPR + 128 AGPR)

#define NL2E  (-1.44269504088896f)   // -log2(e)
#define N2L2E (-2.88539008177793f)   // -2*log2(e)

typedef __bf16 bf16x8 __attribute__((ext_vector_type(8)));
typedef unsigned short u16x8 __attribute__((ext_vector_type(8)));
typedef unsigned short u16x4 __attribute__((ext_vector_type(4)));
typedef float f32x4 __attribute__((ext_vector_type(4)));

__device__ __forceinline__ float sigy(float y) {
    return __builtin_amdgcn_rcpf(1.0f + __builtin_amdgcn_exp2f(y));
}
__device__ __forceinline__ float tanhy(float y) {
    return 2.0f * __builtin_amdgcn_rcpf(1.0f + __builtin_amdgcn_exp2f(y)) - 1.0f;
}
__device__ __forceinline__ unsigned short bfbits(float f) {
    return __builtin_bit_cast(unsigned short, (__bf16)f);   // HW RNE cvt
}

#define MFMA(A, B, C) __builtin_amdgcn_mfma_f32_16x16x32_bf16((A), (B), (C), 0, 0, 0)
#define WB(W) __builtin_bit_cast(bf16x8, W)

// R12 = validated R10 structure (8 waves, wave owns 16 hcols x 4 gates,
// one barrier/step, intrinsic MFMA, AGPR-pinned weights) with ONE change:
// the loop body is reordered ih-FIRST. Post-barrier, the h-independent ih
// GEMM (emb[s+1] has been in LDS since the previous step) issues while the
// h ds_reads and the 4-deep hh chains warm up; manual renaming (xq) breaks
// the xp anti-dependence that forced ih after hh. R11's gate-split occupancy
// attempt REGRESSED (44% occ but 2x LDS A-traffic + 2 barriers): reverted.
//
// Swizzle discipline: key = (row&7)<<4 spans BITS 4-6 -> XOR onto the FULL
// logical byte offset (incl. kt*64, bits 6-7), never onto a pre-XORed base.
// No wave-divergent code paths (R6/R7 miscompile at the 256-reg cap).
__global__ __launch_bounds__(BLOCK_T, 2)
void lane_lstm(const float* __restrict__ lanes,
               const float* __restrict__ W_emb, const float* __restrict__ b_emb,
               const float* __restrict__ W_ih,  const float* __restrict__ W_hh,
               const float* __restrict__ b_ih,  const float* __restrict__ b_hh,
               float* __restrict__ out, int BL)
{
    __shared__ __align__(16) float ext_lds[S_LEN * ROWS * 5];           // 16000 B
    __shared__ __align__(16) unsigned short emb_lds[2][MROWS * H_DIM];  // 2x4096 B
    __shared__ __align__(16) unsigned short h_lds[2][MROWS * H_DIM];    // 2x4096 B
    __shared__ int valid_lds[MROWS];

    const int t    = threadIdx.x;
    const int lane = t & 63;
    const int wv   = t >> 6;
    const int row0 = blockIdx.x * ROWS;

    if (t < MROWS) valid_lds[t] = 1;
    {   // h0 = 0 (buffer 0)
        u16x4 z = {0, 0, 0, 0};
        *(u16x4*)((char*)&h_lds[0][0] + t * 8) = z;
    }
    __syncthreads();

    // ---- ext features (x,y,dx,dy,yaw) ----
    for (int p = t; p < S_LEN * ROWS; p += BLOCK_T) {
        int s = p / ROWS;
        int r = p - s * ROWS;
        int bl = row0 + r;
        float x = 0.f, y = 0.f, dx = 0.f, dy = 0.f;
        if (bl < BL) {
            const float* lp = lanes + ((size_t)s * BL + bl) * 2;
            x = lp[0]; y = lp[1];
            if (s > 0) {
                const float* lq = lanes + ((size_t)(s - 1) * BL + bl) * 2;
                dx = x - lq[0]; dy = y - lq[1];
            }
            if (__builtin_isnan(x) || __builtin_isnan(y)) valid_lds[r] = 0;
        }
        float* e = &ext_lds[p * 5];
        e[0] = x; e[1] = y; e[2] = dx; e[3] = dy; e[4] = atan2f(y, x);
    }

    // ---- wave-owned weight B-frags, PRE-SCALED, AGPR-pinned ----
    // B-frag: col = g*128 + wv*16 + (lane&15), k = kt*32 + (lane>>4)*8 + j.
    // Gate scale: i,f,o -> -log2e ; g -> -2log2e (exp2-direct nonlinearities).
    const int hcol = wv * 16 + (lane & 15);
    const int kb0  = (lane >> 4) << 3;
    f32x4 wih[4][4], whh[4][4];
    float bia[4];
    #pragma unroll
    for (int g = 0; g < 4; ++g) {
        const float sc = (g == 2) ? N2L2E : NL2E;
        bia[g] = (b_ih[g * H_DIM + hcol] + b_hh[g * H_DIM + hcol]) * sc;
        #pragma unroll
        for (int kt = 0; kt < 4; ++kt) {
            const float* pa = &W_ih[(size_t)(g * H_DIM + hcol) * H_DIM + kt * 32 + kb0];
            const float* pb = &W_hh[(size_t)(g * H_DIM + hcol) * H_DIM + kt * 32 + kb0];
            u16x8 ta, tb;
            #pragma unroll
            for (int j = 0; j < 8; ++j) { ta[j] = bfbits(pa[j] * sc); tb[j] = bfbits(pb[j] * sc); }
            wih[g][kt] = __builtin_bit_cast(f32x4, ta);
            whh[g][kt] = __builtin_bit_cast(f32x4, tb);
        }
    }
    #pragma unroll
    for (int g = 0; g < 4; ++g) {
        #pragma unroll
        for (int kt = 0; kt < 4; ++kt) {
            asm volatile("" : "+a"(wih[g][kt]));   // pin to AGPR file
            asm volatile("" : "+a"(whh[g][kt]));
        }
    }
    // named bias splats (macro-safe; built once)
    f32x4 bv0, bv1, bv2, bv3;
    bv0[0] = bia[0]; bv0[1] = bia[0]; bv0[2] = bia[0]; bv0[3] = bia[0];
    bv1[0] = bia[1]; bv1[1] = bia[1]; bv1[2] = bia[1]; bv1[3] = bia[1];
    bv2[0] = bia[2]; bv2[1] = bia[2]; bv2[2] = bia[2]; bv2[3] = bia[2];
    bv3[0] = bia[3]; bv3[1] = bia[3]; bv3[2] = bia[3]; bv3[3] = bia[3];

    // ---- per-thread emb constants (thread t -> row t>>5, hcols (t&31)*4..+3) ----
    const int er  = t >> 5;
    const int ec0 = (t & 31) << 2;
    float wemb[4][5], bemb[4];
    #pragma unroll
    for (int j = 0; j < 4; ++j) {
        #pragma unroll
        for (int d = 0; d < 5; ++d) wemb[j][d] = W_emb[(ec0 + j) * 5 + d];
        bemb[j] = b_emb[ec0 + j];
    }
    const int ebyte = ((er << 8) + (ec0 << 1)) ^ ((er & 7) << 4);

    auto emb_store = [&](int s, int b) {
        float x0 = 0.f, x1 = 0.f, x2 = 0.f, x3 = 0.f, x4 = 0.f;
        if (er < ROWS && valid_lds[er] && row0 + er < BL) {
            const float* e = &ext_lds[(s * ROWS + er) * 5];
            x0 = e[0]; x1 = e[1]; x2 = e[2]; x3 = e[3]; x4 = e[4];
        }
        u16x4 ev;
        #pragma unroll
        for (int j = 0; j < 4; ++j) {
            float a = bemb[j];
            a += wemb[j][0] * x0; a += wemb[j][1] * x1; a += wemb[j][2] * x2;
            a += wemb[j][3] * x3; a += wemb[j][4] * x4;
            ev[j] = bfbits(fmaxf(a, 0.f));
        }
        *(u16x4*)((char*)&emb_lds[b][0] + ebyte) = ev;
    };

    const int arow  = lane & 15;
    const int akey  = (arow & 7) << 4;
    const int abase = (arow << 8) + ((lane >> 4) << 4);
    const int crow  = (lane >> 4) << 2;   // C/D (m89): row=(lane>>4)*4+i, col=lane&15

    __syncthreads();       // ext + valid + h0 ready
    emb_store(0, 0);
    __syncthreads();       // emb[0] visible

    // ---- prologue: xp = bias + emb[0] @ W_ih^T ----
    f32x4 xp0, xp1, xp2, xp3;
    {
        const char* eb = (const char*)&emb_lds[0][0];
        bf16x8 e0 = *(const bf16x8*)(eb + ((abase + 0 * 64) ^ akey));
        bf16x8 e1 = *(const bf16x8*)(eb + ((abase + 1 * 64) ^ akey));
        bf16x8 e2 = *(const bf16x8*)(eb + ((abase + 2 * 64) ^ akey));
        bf16x8 e3 = *(const bf16x8*)(eb + ((abase + 3 * 64) ^ akey));
        xp0 = MFMA(e0, WB(wih[0][0]), bv0);
        xp0 = MFMA(e1, WB(wih[0][1]), xp0);
        xp0 = MFMA(e2, WB(wih[0][2]), xp0);
        xp0 = MFMA(e3, WB(wih[0][3]), xp0);
        xp1 = MFMA(e0, WB(wih[1][0]), bv1);
        xp1 = MFMA(e1, WB(wih[1][1]), xp1);
        xp1 = MFMA(e2, WB(wih[1][2]), xp1);
        xp1 = MFMA(e3, WB(wih[1][3]), xp1);
        xp2 = MFMA(e0, WB(wih[2][0]), bv2);
        xp2 = MFMA(e1, WB(wih[2][1]), xp2);
        xp2 = MFMA(e2, WB(wih[2][2]), xp2);
        xp2 = MFMA(e3, WB(wih[2][3]), xp2);
        xp3 = MFMA(e0, WB(wih[3][0]), bv3);
        xp3 = MFMA(e1, WB(wih[3][1]), xp3);
        xp3 = MFMA(e2, WB(wih[3][2]), xp3);
        xp3 = MFMA(e3, WB(wih[3][3]), xp3);
    }
    emb_store(1, 1);
    __syncthreads();       // emb[1] visible

    float c0 = 0.f, c1 = 0.f, c2 = 0.f, c3 = 0.f;

    for (int s = 0; s < S_LEN - 1; ++s) {
        const char* hb = (const char*)&h_lds[s & 1][0];
        const char* en = (const char*)&emb_lds[(s + 1) & 1][0];   // emb[s+1]

        // ---- issue ALL LDS reads up front (latency in flight under ih) ----
        bf16x8 ah0 = *(const bf16x8*)(hb + ((abase + 0 * 64) ^ akey));
        bf16x8 ah1 = *(const bf16x8*)(hb + ((abase + 1 * 64) ^ akey));
        bf16x8 ah2 = *(const bf16x8*)(hb + ((abase + 2 * 64) ^ akey));
        bf16x8 ah3 = *(const bf16x8*)(hb + ((abase + 3 * 64) ^ akey));
        bf16x8 ae0 = *(const bf16x8*)(en + ((abase + 0 * 64) ^ akey));
        bf16x8 ae1 = *(const bf16x8*)(en + ((abase + 1 * 64) ^ akey));
        bf16x8 ae2 = *(const bf16x8*)(en + ((abase + 2 * 64) ^ akey));
        bf16x8 ae3 = *(const bf16x8*)(en + ((abase + 3 * 64) ^ akey));

        // ---- ih GEMM FIRST (h-independent; renamed into xq to break the
        // anti-dependence on xp that previously forced it after hh) ----
        f32x4 xq0 = MFMA(ae0, WB(wih[0][0]), bv0);
        xq0 = MFMA(ae1, WB(wih[0][1]), xq0);
        xq0 = MFMA(ae2, WB(wih[0][2]), xq0);
        xq0 = MFMA(ae3, WB(wih[0][3]), xq0);
        f32x4 xq1 = MFMA(ae0, WB(wih[1][0]), bv1);
        xq1 = MFMA(ae1, WB(wih[1][1]), xq1);
        xq1 = MFMA(ae2, WB(wih[1][2]), xq1);
        xq1 = MFMA(ae3, WB(wih[1][3]), xq1);
        f32x4 xq2 = MFMA(ae0, WB(wih[2][0]), bv2);
        xq2 = MFMA(ae1, WB(wih[2][1]), xq2);
        xq2 = MFMA(ae2, WB(wih[2][2]), xq2);
        xq2 = MFMA(ae3, WB(wih[2][3]), xq2);
        f32x4 xq3 = MFMA(ae0, WB(wih[3][0]), bv3);
        xq3 = MFMA(ae1, WB(wih[3][1]), xq3);
        xq3 = MFMA(ae2, WB(wih[3][2]), xq3);
        xq3 = MFMA(ae3, WB(wih[3][3]), xq3);

        // ---- hh GEMM: g = xp[s] + h[s] @ W_hh^T ----
        f32x4 g0 = MFMA(ah0, WB(whh[0][0]), xp0);
        g0 = MFMA(ah1, WB(whh[0][1]), g0);
        g0 = MFMA(ah2, WB(whh[0][2]), g0);
        g0 = MFMA(ah3, WB(whh[0][3]), g0);
        f32x4 g1 = MFMA(ah0, WB(whh[1][0]), xp1);
        g1 = MFMA(ah1, WB(whh[1][1]), g1);
        g1 = MFMA(ah2, WB(whh[1][2]), g1);
        g1 = MFMA(ah3, WB(whh[1][3]), g1);
        f32x4 g2 = MFMA(ah0, WB(whh[2][0]), xp2);
        g2 = MFMA(ah1, WB(whh[2][1]), g2);
        g2 = MFMA(ah2, WB(whh[2][2]), g2);
        g2 = MFMA(ah3, WB(whh[2][3]), g2);
        f32x4 g3 = MFMA(ah0, WB(whh[3][0]), xp3);
        g3 = MFMA(ah1, WB(whh[3][1]), g3);
        g3 = MFMA(ah2, WB(whh[3][2]), g3);
        g3 = MFMA(ah3, WB(whh[3][3]), g3);

        // ---- cell (trans chains drain under the hh/ih MFMA tail) ----
        float hv0, hv1, hv2, hv3;
        c0 = sigy(g1[0]) * c0 + sigy(g0[0]) * tanhy(g2[0]);  hv0 = sigy(g3[0]) * tanhy(c0 * N2L2E);
        c1 = sigy(g1[1]) * c1 + sigy(g0[1]) * tanhy(g2[1]);  hv1 = sigy(g3[1]) * tanhy(c1 * N2L2E);
        c2 = sigy(g1[2]) * c2 + sigy(g0[2]) * tanhy(g2[2]);  hv2 = sigy(g3[2]) * tanhy(c2 * N2L2E);
        c3 = sigy(g1[3]) * c3 + sigy(g0[3]) * tanhy(g2[3]);  hv3 = sigy(g3[3]) * tanhy(c3 * N2L2E);

        if (s + 2 < S_LEN) emb_store(s + 2, s & 1);

        // ---- h -> bf16 LDS (next buffer) ----
        {
            char* hn = (char*)&h_lds[(s + 1) & 1][0];
            #pragma unroll
            for (int i = 0; i < 4; ++i) {
                const float hvi = (i == 0) ? hv0 : (i == 1) ? hv1 : (i == 2) ? hv2 : hv3;
                const int r = crow + i;
                const int byte = ((r << 8) + (hcol << 1)) ^ ((r & 7) << 4);
                *(unsigned short*)(hn + byte) = bfbits(hvi);
            }
        }

        // rename for next iteration (compiler coalesces; no copies emitted)
        xp0 = xq0; xp1 = xq1; xp2 = xq2; xp3 = xq3;

        __syncthreads();   // one barrier/step
    }

    // ---- peeled final step s = S_LEN-1: hh + cell + global out ----
    {
        const char* hb = (const char*)&h_lds[(S_LEN - 1) & 1][0];
        bf16x8 ah0 = *(const bf16x8*)(hb + ((abase + 0 * 64) ^ akey));
        bf16x8 ah1 = *(const bf16x8*)(hb + ((abase + 1 * 64) ^ akey));
        bf16x8 ah2 = *(const bf16x8*)(hb + ((abase + 2 * 64) ^ akey));
        bf16x8 ah3 = *(const bf16x8*)(hb + ((abase + 3 * 64) ^ akey));
        f32x4 g0 = MFMA(ah0, WB(whh[0][0]), xp0);
        g0 = MFMA(ah1, WB(whh[0][1]), g0);
        g0 = MFMA(ah2, WB(whh[0][2]), g0);
        g0 = MFMA(ah3, WB(whh[0][3]), g0);
        f32x4 g1 = MFMA(ah0, WB(whh[1][0]), xp1);
        g1 = MFMA(ah1, WB(whh[1][1]), g1);
        g1 = MFMA(ah2, WB(whh[1][2]), g1);
        g1 = MFMA(ah3, WB(whh[1][3]), g1);
        f32x4 g2 = MFMA(ah0, WB(whh[2][0]), xp2);
        g2 = MFMA(ah1, WB(whh[2][1]), g2);
        g2 = MFMA(ah2, WB(whh[2][2]), g2);
        g2 = MFMA(ah3, WB(whh[2][3]), g2);
        f32x4 g3 = MFMA(ah0, WB(whh[3][0]), xp3);
        g3 = MFMA(ah1, WB(whh[3][1]), g3);
        g3 = MFMA(ah2, WB(whh[3][2]), g3);
        g3 = MFMA(ah3, WB(whh[3][3]), g3);

        float hv0, hv1, hv2, hv3;
        c0 = sigy(g1[0]) * c0 + sigy(g0[0]) * tanhy(g2[0]);  hv0 = sigy(g3[0]) * tanhy(c0 * N2L2E);
        c1 = sigy(g1[1]) * c1 + sigy(g0[1]) * tanhy(g2[1]);  hv1 = sigy(g3[1]) * tanhy(c1 * N2L2E);
        c2 = sigy(g1[2]) * c2 + sigy(g0[2]) * tanhy(g2[2]);  hv2 = sigy(g3[2]) * tanhy(c2 * N2L2E);
        c3 = sigy(g1[3]) * c3 + sigy(g0[3]) * tanhy(g2[3]);  hv3 = sigy(g3[3]) * tanhy(c3 * N2L2E);

        #pragma unroll
        for (int i = 0; i < 4; ++i) {
            const float hvi = (i == 0) ? hv0 : (i == 1) ? hv1 : (i == 2) ? hv2 : hv3;
            const int r = crow + i;
            if (r < ROWS && row0 + r < BL)
                out[(size_t)(row0 + r) * H_DIM + hcol] = hvi;
        }
    }
}

extern "C" void kernel_launch(void* const* d_in, const int* in_sizes, int n_in,
                              void* d_out, int out_size, void* d_ws, size_t ws_size,
                              hipStream_t stream) {
    const float* lanes = (const float*)d_in[1];
    const float* W_emb = (const float*)d_in[2];
    const float* b_emb = (const float*)d_in[3];
    const float* W_ih  = (const float*)d_in[4];
    const float* W_hh  = (const float*)d_in[5];
    const float* b_ih  = (const float*)d_in[6];
    const float* b_hh  = (const float*)d_in[7];
    float* out = (float*)d_out;

    const int BL   = in_sizes[1] / (2 * S_LEN);   // 2560
    const int grid = (BL + ROWS - 1) / ROWS;      // 256 blocks -> 1 per CU

    lane_lstm<<<dim3(grid), dim3(BLOCK_T), 0, stream>>>(
        lanes, W_emb, b_emb, W_ih, W_hh, b_ih, b_hh, out, BL);
}